// Round 6
// baseline (193.322 us; speedup 1.0000x reference)
//
#include <hip/hip_runtime.h>

// YOLOv1-style loss: S=7, B=2, C=20, L=49, n=16384.
// preds row: [ pcls: 980 | pconf: 98 | pbox: 392 ] = 1470 floats
// labels row: L * [ obj(1) | tcls(20) | tbox(4) ] = 1225 floats
// Weights: NOOBJ=0.5, OBJ=0.5, CLS=0.5, COORD=2.5
//
// R6: software-pipelined 4-cells-per-thread, no LDS staging.
// Evidence: R3 (all-scattered) == R5 (labels LDS-staged) == ~51us -> the
// limiter is the 2-deep dependent-load chain / low bytes-in-flight (Little's
// law: need ~10KB/CU in flight, had ~1KB), not the access pattern.
// Stage A issues ALL independent loads for 4 cells (obj flag, conf float2,
// tbox unconditionally -- tbox rides the same labels lines as the flag, so
// zero extra HBM traffic); stage B does the obj-gated cls/box gathers.
// Strided cell mapping (t, t+Q, t+2Q, t+3Q; Q=200704=4096 rows) keeps
// lane-adjacent threads cell-adjacent (R3 coalescing). 784 blocks.

#define L_CELLS 49
#define PRED_ROW 1470
#define LAB_ROW 1225
#define CONF_BASE 980
#define BOX_BASE 1078
#define W_NOOBJ 0.5f
#define W_OBJ 0.5f
#define W_CLS 0.5f
#define W_COORD 2.5f
#define INV_S (1.0f / 7.0f)

__global__ __launch_bounds__(256) void yolo_loss_kernel(
    const float* __restrict__ preds, const float* __restrict__ labels,
    float* __restrict__ ws, int quarter) {
  const int t = blockIdx.x * 256 + threadIdx.x;

  // ---- stage A: independent loads for all 4 cells ----
  const float* labc[4];
  const float* rp[4];
  int l[4];
  float objf[4];
  float2 cf[4];
  float tb[4][4];
#pragma unroll
  for (int j = 0; j < 4; ++j) {
    int c = t + j * quarter;
    int s = c / L_CELLS;  // compiler magic-mul
    int li = c - s * L_CELLS;
    const float* lb = labels + (size_t)s * LAB_ROW + 25 * li;
    const float* pp = preds + (size_t)s * PRED_ROW;
    labc[j] = lb;
    rp[j] = pp;
    l[j] = li;
    objf[j] = lb[0];                                   // obj flag
    cf[j] = *(const float2*)(pp + CONF_BASE + 2 * li); // conf (8B aligned)
    tb[j][0] = lb[21];  // tbox unconditional: same cache lines as lb[0]
    tb[j][1] = lb[22];
    tb[j][2] = lb[23];
    tb[j][3] = lb[24];
  }

  // ---- stage B: per-cell compute; obj-gated gathers ----
  float acc = 0.0f;
#pragma unroll
  for (int j = 0; j < 4; ++j) {
    float c0 = cf[j].x, c1 = cf[j].y;
    if (objf[j] != 0.0f) {
      const float* pp = rp[j];
      const int li = l[j];
      float bx[8];
#pragma unroll
      for (int k = 0; k < 4; ++k) {
        float2 v = *(const float2*)(pp + BOX_BASE + 8 * li + 2 * k);
        bx[2 * k] = v.x;
        bx[2 * k + 1] = v.y;
      }
      float tx = tb[j][0], ty = tb[j][1], tw = tb[j][2], th = tb[j][3];
      float t0 = tx * INV_S, t1 = ty * INV_S, t2 = tw, t3 = th;

      float iou[2], rmse2[2];
#pragma unroll
      for (int b = 0; b < 2; ++b) {
        float o0 = bx[4 * b + 0] * INV_S;
        float o1 = bx[4 * b + 1] * INV_S;
        float o2 = bx[4 * b + 2] * bx[4 * b + 2];
        float o3 = bx[4 * b + 3] * bx[4 * b + 3];
        float left = fmaxf(t0 - 0.5f * t2, o0 - 0.5f * o2);
        float right = fminf(t0 + 0.5f * t2, o0 + 0.5f * o2);
        float top = fmaxf(t1 - 0.5f * t3, o1 - 0.5f * o3);
        float bot = fminf(t1 + 0.5f * t3, o1 + 0.5f * o3);
        float wd = right - left;
        float h = bot - top;
        bool invalid = (wd < 0.0f) || (h < 0.0f);
        float inter = invalid ? 0.0f : wd * h;
        float uni = t2 * t3 + o2 * o3 - inter;
        iou[b] = invalid ? 0.0f : inter / fmaxf(uni, 1e-12f);
        float d0 = t0 - o0, d1 = t1 - o1, d2 = t2 - o2, d3 = t3 - o3;
        rmse2[b] = d0 * d0 + d1 * d1 + d2 * d2 + d3 * d3;  // sqrt monotone
      }

      float max_iou = fmaxf(iou[0], iou[1]);
      // jnp.argmax/argmin: first index wins ties -> strict compare for idx 1
      int best;
      if (max_iou > 0.0f)
        best = (iou[1] > iou[0]) ? 1 : 0;
      else
        best = (rmse2[1] < rmse2[0]) ? 1 : 0;
      float best_iou = iou[best];

      float cb = (best == 0) ? c0 : c1;
      float co = (best == 0) ? c1 : c0;
      float db = best_iou - cb;
      acc += W_OBJ * db * db + W_NOOBJ * co * co;

      // cls: 10x float2 (8B aligned), tcls scalar from labels lines
      const float* lb = labc[j];
      float clsacc = 0.0f;
#pragma unroll
      for (int k = 0; k < 10; ++k) {
        float2 p = *(const float2*)(pp + 20 * li + 2 * k);
        float d0 = lb[1 + 2 * k] - p.x;
        float d1 = lb[2 + 2 * k] - p.y;
        clsacc += d0 * d0 + d1 * d1;
      }
      acc += W_CLS * clsacc;

      // coord: (tx, ty, sqrt(tw), sqrt(th)) vs best raw box
      float e0 = tx - bx[best * 4 + 0];
      float e1 = ty - bx[best * 4 + 1];
      float e2 = sqrtf(tw) - bx[best * 4 + 2];
      float e3 = sqrtf(th) - bx[best * 4 + 3];
      acc += W_COORD * (e0 * e0 + e1 * e1 + e2 * e2 + e3 * e3);
    } else {
      acc += W_NOOBJ * (c0 * c0 + c1 * c1);
    }
  }

  // ---- reduce: wave(64) shuffle -> LDS -> one ws slot per block ----
#pragma unroll
  for (int o = 32; o > 0; o >>= 1) acc += __shfl_down(acc, o);

  __shared__ float wsum[4];
  int wave = threadIdx.x >> 6;
  int lane = threadIdx.x & 63;
  if (lane == 0) wsum[wave] = acc;
  __syncthreads();
  if (threadIdx.x == 0) ws[blockIdx.x] = wsum[0] + wsum[1] + wsum[2] + wsum[3];
}

__global__ __launch_bounds__(1024) void final_reduce_kernel(
    const float* __restrict__ ws, float* __restrict__ out, int m) {
  // m <= 1024: single pass, no serial loop
  float acc = (threadIdx.x < m) ? ws[threadIdx.x] : 0.0f;
#pragma unroll
  for (int o = 32; o > 0; o >>= 1) acc += __shfl_down(acc, o);
  __shared__ float wsum[16];
  int wave = threadIdx.x >> 6;
  int lane = threadIdx.x & 63;
  if (lane == 0) wsum[wave] = acc;
  __syncthreads();
  if (threadIdx.x == 0) {
    float s = 0.0f;
#pragma unroll
    for (int i = 0; i < 16; ++i) s += wsum[i];
    out[0] = s;
  }
}

extern "C" void kernel_launch(void* const* d_in, const int* in_sizes, int n_in,
                              void* d_out, int out_size, void* d_ws, size_t ws_size,
                              hipStream_t stream) {
  const float* preds = (const float*)d_in[0];
  const float* labels = (const float*)d_in[1];
  float* out = (float*)d_out;
  float* ws = (float*)d_ws;
  int n = in_sizes[0] / PRED_ROW;    // 16384
  int total = n * L_CELLS;           // 802816
  int quarter = total / 4;           // 200704 (= 4096 whole samples)
  int blocks = quarter / 256;        // 784

  yolo_loss_kernel<<<blocks, 256, 0, stream>>>(preds, labels, ws, quarter);
  final_reduce_kernel<<<1, 1024, 0, stream>>>(ws, out, blocks);
}

// Round 7
// 188.198 us; speedup vs baseline: 1.0272x; 1.0272x over previous
//
#include <hip/hip_runtime.h>

// YOLOv1-style loss: S=7, B=2, C=20, L=49, n=16384.
// preds row: [ pcls: 980 | pconf: 98 | pbox: 392 ] = 1470 floats
// labels row: L * [ obj(1) | tcls(20) | tbox(4) ] = 1225 floats
// Weights: NOOBJ=0.5, OBJ=0.5, CLS=0.5, COORD=2.5
//
// R7: wave-per-sample, branch-free wide staging for max bytes-in-flight.
// Evidence: R3/R5 ~51us, R6 57us@28% occ -- delivered rate pinned ~1.3 TB/s
// because outstanding HBM bytes/CU ~2-3KB (ws-fill evicts L3 each timed
// iter -> ~900cy misses; dependent/gated loads + low ILPxocc). Fix: each
// wave stages labels row (308 fl4) + conf (25 fl4) + pbox (99 fl4) as ~8
// independent float4 loads/lane, unconditional, wave-private LDS, NO
// __syncthreads (R5-proven). 128B/lane x 20 waves/CU ~160KB/CU in flight.
// Only 15%-gated pcls gathers remain direct. LDS 27.8KB -> 5 blk/CU.

#define L_CELLS 49
#define PRED_ROW 1470
#define LAB_ROW 1225
#define CONF_BASE 980
#define BOX_BASE 1078
#define W_NOOBJ 0.5f
#define W_OBJ 0.5f
#define W_CLS 0.5f
#define W_COORD 2.5f
#define INV_S (1.0f / 7.0f)

#define LAB_SLOTS 308  // ceil((3 + 1225)/4)
#define CONF_OFS 308   // 25 slots
#define BOX_OFS 333    // 99 slots
#define WAVE_SLOTS 434 // 432 + pad

__global__ __launch_bounds__(256) void yolo_loss_kernel(
    const float* __restrict__ preds, const float* __restrict__ labels,
    float* __restrict__ ws) {
  __shared__ float4 st[4][WAVE_SLOTS];

  const int tid = threadIdx.x;
  const int w = tid >> 6;
  const int lane = tid & 63;
  const int s = blockIdx.x * 4 + w;
  float4* stw = st[w];

  // ---- stage: all unconditional float4 loads, issued back-to-back ----
  // labels row (align-down; <=12B page-safe overread on final row)
  size_t g0 = (size_t)s * LAB_ROW;
  size_t ga = g0 & ~(size_t)3;
  int loff = (int)(g0 - ga);
#pragma unroll
  for (int r = 0; r < 5; ++r) {
    int i = lane + 64 * r;
    if (i < LAB_SLOTS) stw[i] = *(const float4*)(labels + ga + 4 * (size_t)i);
  }
  // conf region (98 floats; coff=0 or 2, 25 slots exact)
  size_t c0 = (size_t)s * PRED_ROW + CONF_BASE;
  size_t ca = c0 & ~(size_t)3;
  int coff = (int)(c0 - ca);
  if (lane < 25)
    stw[CONF_OFS + lane] = *(const float4*)(preds + ca + 4 * (size_t)lane);
  // pbox region (392 floats; <=16B overread past final row, page-safe)
  size_t b0 = (size_t)s * PRED_ROW + BOX_BASE;
  size_t ba = b0 & ~(size_t)3;
  int boff = (int)(b0 - ba);
#pragma unroll
  for (int r = 0; r < 2; ++r) {
    int i = lane + 64 * r;
    if (i < 99) stw[BOX_OFS + i] = *(const float4*)(preds + ba + 4 * (size_t)i);
  }

  const float* lab = (const float*)stw + loff;              // lab[25l + k]
  const float* cfp = (const float*)(stw + CONF_OFS) + coff; // cfp[2l + k]
  const float* bxp = (const float*)(stw + BOX_OFS) + boff;  // bxp[8l + k]
  const float* rp = preds + (size_t)s * PRED_ROW;

  float acc = 0.0f;
  if (lane < L_CELLS) {
    const int l = lane;
    float c0v = cfp[2 * l], c1v = cfp[2 * l + 1];
    float objf = lab[25 * l];

    if (objf != 0.0f) {
      float bx[8];
#pragma unroll
      for (int k = 0; k < 8; ++k) bx[k] = bxp[8 * l + k];
      float tx = lab[25 * l + 21], ty = lab[25 * l + 22];
      float tw = lab[25 * l + 23], th = lab[25 * l + 24];
      float t0 = tx * INV_S, t1 = ty * INV_S, t2 = tw, t3 = th;

      float iou[2], rmse2[2];
#pragma unroll
      for (int b = 0; b < 2; ++b) {
        float o0 = bx[4 * b + 0] * INV_S;
        float o1 = bx[4 * b + 1] * INV_S;
        float o2 = bx[4 * b + 2] * bx[4 * b + 2];
        float o3 = bx[4 * b + 3] * bx[4 * b + 3];
        float left = fmaxf(t0 - 0.5f * t2, o0 - 0.5f * o2);
        float right = fminf(t0 + 0.5f * t2, o0 + 0.5f * o2);
        float top = fmaxf(t1 - 0.5f * t3, o1 - 0.5f * o3);
        float bot = fminf(t1 + 0.5f * t3, o1 + 0.5f * o3);
        float wd = right - left;
        float h = bot - top;
        bool invalid = (wd < 0.0f) || (h < 0.0f);
        float inter = invalid ? 0.0f : wd * h;
        float uni = t2 * t3 + o2 * o3 - inter;
        iou[b] = invalid ? 0.0f : inter / fmaxf(uni, 1e-12f);
        float d0 = t0 - o0, d1 = t1 - o1, d2 = t2 - o2, d3 = t3 - o3;
        rmse2[b] = d0 * d0 + d1 * d1 + d2 * d2 + d3 * d3;  // sqrt monotone
      }

      float max_iou = fmaxf(iou[0], iou[1]);
      // jnp.argmax/argmin: first index wins ties -> strict compare for idx 1
      int best;
      if (max_iou > 0.0f)
        best = (iou[1] > iou[0]) ? 1 : 0;
      else
        best = (rmse2[1] < rmse2[0]) ? 1 : 0;
      float best_iou = iou[best];

      float cb = (best == 0) ? c0v : c1v;
      float co = (best == 0) ? c1v : c0v;
      float db = best_iou - cb;
      acc += W_OBJ * db * db + W_NOOBJ * co * co;

      // cls: pcls direct from global (10x float2, 8B aligned, ~15% lanes),
      // tcls from staged labels
      float clsacc = 0.0f;
#pragma unroll
      for (int k = 0; k < 10; ++k) {
        float2 p = *(const float2*)(rp + 20 * l + 2 * k);
        float d0 = lab[25 * l + 1 + 2 * k] - p.x;
        float d1 = lab[25 * l + 2 + 2 * k] - p.y;
        clsacc += d0 * d0 + d1 * d1;
      }
      acc += W_CLS * clsacc;

      // coord: (tx, ty, sqrt(tw), sqrt(th)) vs best raw box
      float e0 = tx - bx[best * 4 + 0];
      float e1 = ty - bx[best * 4 + 1];
      float e2 = sqrtf(tw) - bx[best * 4 + 2];
      float e3 = sqrtf(th) - bx[best * 4 + 3];
      acc += W_COORD * (e0 * e0 + e1 * e1 + e2 * e2 + e3 * e3);
    } else {
      acc += W_NOOBJ * (c0v * c0v + c1v * c1v);
    }
  }

  // ---- reduce: wave(64) shuffle -> LDS -> one ws slot per block ----
#pragma unroll
  for (int o = 32; o > 0; o >>= 1) acc += __shfl_down(acc, o);

  __shared__ float wsum[4];
  if (lane == 0) wsum[w] = acc;
  __syncthreads();
  if (tid == 0) ws[blockIdx.x] = wsum[0] + wsum[1] + wsum[2] + wsum[3];
}

__global__ __launch_bounds__(1024) void final_reduce_kernel(
    const float* __restrict__ ws, float* __restrict__ out, int m) {
  float acc = 0.0f;
  for (int i = threadIdx.x; i < m; i += 1024) acc += ws[i];
#pragma unroll
  for (int o = 32; o > 0; o >>= 1) acc += __shfl_down(acc, o);
  __shared__ float wsum[16];
  int wave = threadIdx.x >> 6;
  int lane = threadIdx.x & 63;
  if (lane == 0) wsum[wave] = acc;
  __syncthreads();
  if (threadIdx.x == 0) {
    float sum = 0.0f;
#pragma unroll
    for (int i = 0; i < 16; ++i) sum += wsum[i];
    out[0] = sum;
  }
}

extern "C" void kernel_launch(void* const* d_in, const int* in_sizes, int n_in,
                              void* d_out, int out_size, void* d_ws, size_t ws_size,
                              hipStream_t stream) {
  const float* preds = (const float*)d_in[0];
  const float* labels = (const float*)d_in[1];
  float* out = (float*)d_out;
  float* ws = (float*)d_ws;
  int n = in_sizes[0] / PRED_ROW;  // 16384
  int blocks = n / 4;              // 4096 (wave per sample)

  yolo_loss_kernel<<<blocks, 256, 0, stream>>>(preds, labels, ws);
  final_reduce_kernel<<<1, 1024, 0, stream>>>(ws, out, blocks);
}